// Round 7
// baseline (92.889 us; speedup 1.0000x reference)
//
#include <hip/hip_runtime.h>
#include <math.h>

// Problem constants (fixed by the reference):
constexpr int B = 4, C = 64, N = 65536, K = 16;
// Channel slicing: 2 slices of 32 channels; bf16 row = 64 B (one L2 sector).
constexpr int NSLICE = 2, CS = 32;

// Round-to-nearest-even fp32 -> bf16 (inputs are finite normals).
__device__ __forceinline__ unsigned short f2bf(float x) {
  unsigned int u = __float_as_uint(x);
  unsigned int r = (u + 0x7FFFu + ((u >> 16) & 1u)) >> 16;
  return (unsigned short)r;
}

// ---------------------------------------------------------------------------
// Kernel 1: transpose + convert + slice:
// f fp32 [B, C, N] -> ft bf16 [slice][B][N][32]  (64 B rows per slice).
// 64x64 tiles through padded LDS; coalesced reads; ushort2 packed stores.
// ---------------------------------------------------------------------------
__global__ __launch_bounds__(256) void transpose_bf16_kernel(
    const float* __restrict__ f, unsigned short* __restrict__ ft) {
  __shared__ float tile[64][65];
  const int n0 = blockIdx.x * 64;
  const int b  = blockIdx.y;
  const float* fb = f + (size_t)b * C * N;
  const int tx = threadIdx.x;  // 0..63
  const int ty = threadIdx.y;  // 0..3
  const int t  = ty * 64 + tx;

#pragma unroll
  for (int i = 0; i < 64; i += 4) {
    const int c = ty + i;
    tile[c][tx] = fb[(size_t)c * N + n0 + tx];  // coalesced along n
  }
  __syncthreads();

  // Store phase: thread t -> (c-pair c2 = t&31, n = (t>>5) + 8*i).
  // c = 2*c2 is even, so both channels of the pair land in the same slice.
  const int c2    = t & 31;
  const int nbase = t >> 5;
  const int c     = 2 * c2;
  const int slice = c >> 5;   // 0 or 1
  const int coff  = c & 31;
  unsigned short* fts = ft + ((size_t)slice * B + b) * N * CS;
#pragma unroll
  for (int i = 0; i < 64; i += 8) {
    const int n  = nbase + i;
    const float lo = tile[c][n];
    const float hi = tile[c + 1][n];
    ushort2 pk;
    pk.x = f2bf(lo);
    pk.y = f2bf(hi);
    *reinterpret_cast<ushort2*>(&fts[(size_t)(n0 + n) * CS + coff]) = pk;
  }
}

// ---------------------------------------------------------------------------
// Kernel 2: gather-max v7 — L2-resident sliced table.
// Fetch-path model (R1..R6): dur ~= FETCH_SIZE / ~3 TB/s. So minimize L2
// misses: per (slice, b) phase the active table is 4 MB -> fits per-XCD L2.
// Grid linearized phase-major: bx = ((slice*4 + b) << 10) | nblk, so dispatch
// order processes one 4 MB table at a time.
// Block = 4 waves x 16 n. Lane (g = lane>>2 -> n, q = lane&3 -> channel
// octet): one gather instr = 16 rows x 64 B, fully coalesced. acc[8] stays
// in registers across all 16 k; single LDS tile round-trip per wave for the
// n<->c transpose (wave-private, no __syncthreads).
// ---------------------------------------------------------------------------
__global__ __launch_bounds__(256, 4) void gather_max_v7(
    const unsigned short* __restrict__ ft, const int* __restrict__ nb,
    float* __restrict__ out) {
  __shared__ int   idx_s[4][K][16];  // [wave][k][n within wave's 16]
  __shared__ float tile[4][16][36];  // per-wave [n 16][c 32 + pad 4]

  const int t    = threadIdx.x;
  const int wave = t >> 6;
  const int lane = t & 63;
  const int g    = lane >> 2;  // 0..15 : n within wave's 16
  const int q    = lane & 3;   // channel octet: c = 8q .. 8q+7 within slice
  const unsigned bx = blockIdx.x;
  const int nblk  = bx & 1023;
  const int phase = bx >> 10;  // 0..7
  const int b     = phase & 3;
  const int slice = phase >> 2;
  const int wn0   = nblk * 64 + wave * 16;  // this wave's first n

  const unsigned short* fts  = ft + ((size_t)slice * B + b) * N * CS;
  const int*            nbb  = nb + (size_t)b * K * N;
  float*                outb = out + (size_t)b * C * N + (size_t)slice * CS * N;

  // Wave-private idx staging: lane (kq = lane>>4, nn = lane&15); 4 loads of
  // 4x64B segments cover k = 0..15 for the wave's 16 n. No barrier needed.
  const int kq = lane >> 4;
  const int nn = lane & 15;
#pragma unroll
  for (int i = 0; i < 4; ++i) {
    const int k = i * 4 + kq;
    idx_s[wave][k][nn] = nbb[(size_t)k * N + wn0 + nn];
  }
  asm volatile("s_waitcnt lgkmcnt(0)" ::: "memory");

  float acc[8];
#pragma unroll
  for (int j = 0; j < 8; ++j) acc[j] = -INFINITY;

#pragma unroll
  for (int kb = 0; kb < 2; ++kb) {  // two 8-deep load batches
    int off[8];
#pragma unroll
    for (int k = 0; k < 8; ++k) off[k] = idx_s[wave][kb * 8 + k][g];

    uint4 v[8];
#pragma unroll
    for (int k = 0; k < 8; ++k) {
      v[k] = *reinterpret_cast<const uint4*>(
          fts + ((size_t)off[k] << 5) + (q << 3));
    }

#pragma unroll
    for (int k = 0; k < 8; ++k) {
      const unsigned int w0 = v[k].x, w1 = v[k].y, w2 = v[k].z, w3 = v[k].w;
      acc[0] = fmaxf(acc[0], __uint_as_float(w0 << 16));
      acc[1] = fmaxf(acc[1], __uint_as_float(w0 & 0xFFFF0000u));
      acc[2] = fmaxf(acc[2], __uint_as_float(w1 << 16));
      acc[3] = fmaxf(acc[3], __uint_as_float(w1 & 0xFFFF0000u));
      acc[4] = fmaxf(acc[4], __uint_as_float(w2 << 16));
      acc[5] = fmaxf(acc[5], __uint_as_float(w2 & 0xFFFF0000u));
      acc[6] = fmaxf(acc[6], __uint_as_float(w3 << 16));
      acc[7] = fmaxf(acc[7], __uint_as_float(w3 & 0xFFFF0000u));
    }
  }

  // One tile write per lane (wave-private, in-order LDS; fence the compiler).
  float4 a0 = make_float4(acc[0], acc[1], acc[2], acc[3]);
  float4 a1 = make_float4(acc[4], acc[5], acc[6], acc[7]);
  *reinterpret_cast<float4*>(&tile[wave][g][q * 8])     = a0;
  *reinterpret_cast<float4*>(&tile[wave][g][q * 8 + 4]) = a1;
  asm volatile("s_waitcnt lgkmcnt(0)" ::: "memory");

  // Transposed store: 16 n x 32 c. lane -> (nn, cc = lane>>4); each
  // instruction stores 4 contiguous 64B segments (one per cc).
  const int cc = lane >> 4;  // 0..3
#pragma unroll
  for (int ci = 0; ci < 8; ++ci) {
    const int c = ci * 4 + cc;
    outb[(size_t)c * N + wn0 + nn] = tile[wave][nn][c];
  }
}

// ---------------------------------------------------------------------------
// Fallback (workspace too small): direct gather, correct but slow.
// ---------------------------------------------------------------------------
__global__ __launch_bounds__(256) void naive_kernel(
    const float* __restrict__ f, const int* __restrict__ nb,
    float* __restrict__ out) {
  const int n = blockIdx.x * 256 + threadIdx.x;
  const int c = blockIdx.y;
  const int b = blockIdx.z;
  if (n >= N) return;
  const float* fb  = f  + (size_t)b * C * N + (size_t)c * N;
  const int*   nbb = nb + (size_t)b * K * N;
  float acc = -INFINITY;
#pragma unroll
  for (int k = 0; k < K; ++k) {
    acc = fmaxf(acc, fb[nbb[(size_t)k * N + n]]);
  }
  out[(size_t)b * C * N + (size_t)c * N + n] = acc;
}

extern "C" void kernel_launch(void* const* d_in, const int* in_sizes, int n_in,
                              void* d_out, int out_size, void* d_ws, size_t ws_size,
                              hipStream_t stream) {
  const float* f   = (const float*)d_in[0];
  const int*   nb  = (const int*)d_in[1];
  float*       out = (float*)d_out;

  const size_t need = (size_t)NSLICE * B * N * CS * sizeof(unsigned short);
  if (ws_size >= need) {
    unsigned short* ft = (unsigned short*)d_ws;
    transpose_bf16_kernel<<<dim3(N / 64, B), dim3(64, 4), 0, stream>>>(f, ft);
    gather_max_v7<<<dim3(NSLICE * B * (N / 64)), 256, 0, stream>>>(ft, nb, out);
  } else {
    naive_kernel<<<dim3((N + 255) / 256, C, B), 256, 0, stream>>>(f, nb, out);
  }
}